// Round 6
// baseline (276.920 us; speedup 1.0000x reference)
//
#include <hip/hip_runtime.h>
#include <math.h>

#define DIM 256
#define HD 32
#define KSCALE (0.17677669529663687f * 1.44269504088896340736f)  /* SCALE*log2(e) */
#define EPS 1e-5f

typedef __attribute__((ext_vector_type(8))) short short8;   // 8 bf16 = 4 VGPRs
typedef __attribute__((ext_vector_type(4))) float f32x4;

union U8 { uint4 u; short8 s; };

__device__ inline unsigned short f2bf(float f) {
    union { float f; unsigned u; } v; v.f = f;
    unsigned r = v.u + 0x7FFF + ((v.u >> 16) & 1);   // RNE
    return (unsigned short)(r >> 16);
}
__device__ inline float bf2f(unsigned short h) {
    union { unsigned u; float f; } v; v.u = ((unsigned)h) << 16;
    return v.f;
}
// pack two fp32 -> two bf16 (round-half-up) in one dword: 3 VALU ops
__device__ inline unsigned pk2bf(float a, float b) {
    unsigned ua = __float_as_uint(a) + 0x8000u;
    unsigned ub = __float_as_uint(b) + 0x8000u;
    return __builtin_amdgcn_perm(ub, ua, 0x07060302u);  // {ub[31:16], ua[31:16]}
}
__device__ inline uint4 pk8bf(float4 a, float4 b) {
    return make_uint4(pk2bf(a.x, a.y), pk2bf(a.z, a.w),
                      pk2bf(b.x, b.y), pk2bf(b.z, b.w));
}
// unpack bf16x2 dword -> 2 fp32
__device__ inline void up2(unsigned u, float& a, float& b) {
    a = __uint_as_float(u << 16);
    b = __uint_as_float(u & 0xffff0000u);
}
#define MFMA16(a, b, c) __builtin_amdgcn_mfma_f32_16x16x32_bf16(a, b, c, 0, 0, 0)
#define EXP2(x) __builtin_amdgcn_exp2f(x)

// ---------------------------------------------------------------------------
// Weights prep: transposed bf16 WqT/WkvT/projT [N][K], conv BwT[o][q*256+i].
// Grid 2048 x 256 (exact 524288 elements).
// ---------------------------------------------------------------------------
__global__ __launch_bounds__(256) void prep_w(
    const float* __restrict__ Wq, const float* __restrict__ Wkv,
    const float* __restrict__ projw, const float* __restrict__ srw,
    unsigned short* __restrict__ WqT, unsigned short* __restrict__ WkvT,
    unsigned short* __restrict__ projT, unsigned short* __restrict__ BwT)
{
    int idx = blockIdx.x * 256 + threadIdx.x;
    if (idx < 65536) { int n = idx >> 8, k = idx & 255; WqT[idx] = f2bf(Wq[(k << 8) + n]); return; }
    idx -= 65536;
    if (idx < 131072) { int n = idx >> 8, k = idx & 255; WkvT[idx] = f2bf(Wkv[(k << 9) + n]); return; }
    idx -= 131072;
    if (idx < 65536) { int n = idx >> 8, k = idx & 255; projT[idx] = f2bf(projw[(k << 8) + n]); return; }
    idx -= 65536;
    { int o = idx >> 10, rem = idx & 1023, q = rem >> 8, i = rem & 255;
      BwT[idx] = f2bf(srw[(o << 10) + (i << 2) + q]); }
}

// ---------------------------------------------------------------------------
// Merged conv (im2col, K=1024) + q-projection (K=256), A staged from fp32
// with on-the-fly bf16 pack. Grid 820 flat blocks.
// ---------------------------------------------------------------------------
__global__ __launch_bounds__(256) void convq_kernel(
    const float* __restrict__ x, const float* __restrict__ y,
    const unsigned short* __restrict__ BwT, const float* __restrict__ srb,
    const unsigned short* __restrict__ WqT,
    unsigned short* __restrict__ redx, unsigned short* __restrict__ redy,
    unsigned short* __restrict__ qxb, unsigned short* __restrict__ qyb)
{
    __shared__ __align__(16) unsigned short At[64][32];
    __shared__ __align__(16) unsigned short Btile[64][32];
    const int tid = threadIdx.x;
    const int lane = tid & 63, w = tid >> 6;
    const int c = lane & 15, quad = lane >> 4;
    const int srow = tid >> 2, sch = (tid & 3) << 3;
    const int bid = blockIdx.x;
    f32x4 acc[4] = {};
    const int rl = (w << 4) + (quad << 2);

    if (bid < 164) {
        // ---------------- conv path ----------------
        const int n0 = (bid & 3) << 6, myi = bid >> 2;
        const float* Xb; unsigned short* Cb; int W, W2, m0;
        if (myi < 25) { Xb = x; Cb = redx; W = 80; W2 = 40; m0 = myi * 64; }
        else {
            const int r = myi - 25, b = r >> 2;
            Xb = y + (size_t)b * 262144; Cb = redy + (size_t)b * 65536;
            W = 32; W2 = 16; m0 = (r & 3) * 64;
        }
        const int p = m0 + srow;
        const int oy = p / W2, ox = p - oy * W2;
        const unsigned short* Bp = BwT + (size_t)(n0 + srow) * 1024 + sch;

        auto addrA = [&](int k0) {
            const int qq = k0 >> 8;
            const int rrow = (2 * oy + (qq >> 1)) * W + 2 * ox + (qq & 1);
            return Xb + (size_t)rrow * DIM + (k0 & 255) + sch;
        };

        const float* ap = addrA(0);
        float4 a0 = *(const float4*)ap, a1 = *(const float4*)(ap + 4);
        uint4 bn = *(const uint4*)Bp;
        for (int k0 = 0; k0 < 1024; k0 += 32) {
            *(uint4*)&At[srow][sch]    = pk8bf(a0, a1);
            *(uint4*)&Btile[srow][sch] = bn;
            if (k0 < 992) {
                const float* np = addrA(k0 + 32);
                a0 = *(const float4*)np; a1 = *(const float4*)(np + 4);
                bn = *(const uint4*)(Bp + k0 + 32);
            }
            __syncthreads();
            short8 a = *(short8*)&At[(w << 4) + c][quad << 3];
            #pragma unroll
            for (int nb = 0; nb < 4; ++nb) {
                short8 b = *(short8*)&Btile[(nb << 4) + c][quad << 3];
                acc[nb] = MFMA16(a, b, acc[nb]);
            }
            __syncthreads();
        }
        #pragma unroll
        for (int nb = 0; nb < 4; ++nb) {
            const int col = n0 + (nb << 4) + c;
            const float bv = srb[col];
            #pragma unroll
            for (int r = 0; r < 4; ++r)
                Cb[(size_t)(m0 + rl + r) * DIM + col] = f2bf(acc[nb][r] + bv);
        }
    } else {
        // ---------------- q-projection path ----------------
        const int r = bid - 164;
        const int n0 = (r & 3) << 6, mg = (r >> 2) << 6;
        const float* Ab = (mg < 6400) ? x + (size_t)mg * 256
                                      : y + (size_t)(mg - 6400) * 256;
        unsigned short* Cb = (mg < 6400) ? qxb + (size_t)mg * 256
                                         : qyb + (size_t)(mg - 6400) * 256;
        const float* Ap = Ab + (size_t)srow * 256 + sch;
        const unsigned short* Bp = WqT + (size_t)(n0 + srow) * 256 + sch;

        float4 a0 = *(const float4*)Ap, a1 = *(const float4*)(Ap + 4);
        uint4 bn = *(const uint4*)Bp;
        for (int k0 = 0; k0 < 256; k0 += 32) {
            *(uint4*)&At[srow][sch]    = pk8bf(a0, a1);
            *(uint4*)&Btile[srow][sch] = bn;
            if (k0 < 224) {
                a0 = *(const float4*)(Ap + k0 + 32);
                a1 = *(const float4*)(Ap + k0 + 36);
                bn = *(const uint4*)(Bp + k0 + 32);
            }
            __syncthreads();
            short8 a = *(short8*)&At[(w << 4) + c][quad << 3];
            #pragma unroll
            for (int nb = 0; nb < 4; ++nb) {
                short8 b = *(short8*)&Btile[(nb << 4) + c][quad << 3];
                acc[nb] = MFMA16(a, b, acc[nb]);
            }
            __syncthreads();
        }
        #pragma unroll
        for (int nb = 0; nb < 4; ++nb) {
            const int col = n0 + (nb << 4) + c;
            #pragma unroll
            for (int r = 0; r < 4; ++r)
                Cb[(size_t)(rl + r) * 256 + col] = f2bf(acc[nb][r]);
        }
    }
}

// ---------------------------------------------------------------------------
// KV projection with fused LayerNorm on A-rows. K cols pre-scaled by KSCALE;
// V written transposed AND tau-permuted within each 64-key block:
//   tau(pos) = 32*(pos>>5) + 8*((pos>>2)&3) + 4*((pos>>4)&1) + (pos&3)
// so the attention PV A-fragment is exactly the in-register packed exp2 of
// the S^T C-fragment (no LDS round-trip, no cross-lane shuffle).
// ---------------------------------------------------------------------------
__global__ __launch_bounds__(256) void kvln_kernel(
    const unsigned short* __restrict__ redx, const unsigned short* __restrict__ redy,
    const unsigned short* __restrict__ WkvT,
    const float* __restrict__ g, const float* __restrict__ bta,
    unsigned short* __restrict__ kbx, unsigned short* __restrict__ vTx,
    unsigned short* __restrict__ kby, unsigned short* __restrict__ vTy)
{
    __shared__ __align__(16) unsigned short At[64][32];
    __shared__ __align__(16) unsigned short Btile[64][32];
    const int tid = threadIdx.x;
    const int lane = tid & 63, w = tid >> 6;
    const int c = lane & 15, quad = lane >> 4;
    const int srow = tid >> 2, sch = (tid & 3) << 3;
    const int bid = blockIdx.x;
    const int n0 = (bid & 7) << 6, mg = (bid >> 3) << 6;
    const unsigned short* Ab = (mg < 1600) ? redx + (size_t)mg * 256
                                           : redy + (size_t)(mg - 1600) * 256;
    const unsigned short* Arow = Ab + (size_t)srow * 256 + sch;

    // ---- row stats ----
    uint4 araw[8];
    float s1 = 0.f, s2 = 0.f;
    #pragma unroll
    for (int ci = 0; ci < 8; ++ci) {
        araw[ci] = *(const uint4*)(Arow + (ci << 5));
        const unsigned* du = (const unsigned*)&araw[ci];
        #pragma unroll
        for (int dd = 0; dd < 4; ++dd) {
            float a, b; up2(du[dd], a, b);
            s1 += a + b; s2 += a * a + b * b;
        }
    }
    s1 += __shfl_xor(s1, 1); s1 += __shfl_xor(s1, 2);
    s2 += __shfl_xor(s2, 1); s2 += __shfl_xor(s2, 2);
    const float mean = s1 * (1.0f / 256.0f);
    const float var  = s2 * (1.0f / 256.0f) - mean * mean;
    const float rstd = rsqrtf(var + EPS);

    // ---- apply LN, repack to bf16 ----
    #pragma unroll
    for (int ci = 0; ci < 8; ++ci) {
        const int ch = (ci << 5) + sch;
        float4 g0 = *(const float4*)(g + ch),   g1 = *(const float4*)(g + ch + 4);
        float4 b0 = *(const float4*)(bta + ch), b1 = *(const float4*)(bta + ch + 4);
        const unsigned* du = (const unsigned*)&araw[ci];
        float v[8];
        #pragma unroll
        for (int dd = 0; dd < 4; ++dd) up2(du[dd], v[2 * dd], v[2 * dd + 1]);
        float4 o0 = make_float4(fmaf((v[0] - mean) * rstd, g0.x, b0.x),
                                fmaf((v[1] - mean) * rstd, g0.y, b0.y),
                                fmaf((v[2] - mean) * rstd, g0.z, b0.z),
                                fmaf((v[3] - mean) * rstd, g0.w, b0.w));
        float4 o1 = make_float4(fmaf((v[4] - mean) * rstd, g1.x, b1.x),
                                fmaf((v[5] - mean) * rstd, g1.y, b1.y),
                                fmaf((v[6] - mean) * rstd, g1.z, b1.z),
                                fmaf((v[7] - mean) * rstd, g1.w, b1.w));
        araw[ci] = pk8bf(o0, o1);
    }

    // ---- GEMM k-loop ----
    const unsigned short* Bp = WkvT + (size_t)(n0 + srow) * 256 + sch;
    uint4 bn = *(const uint4*)Bp;
    f32x4 acc[4] = {};
    for (int k0 = 0; k0 < 256; k0 += 32) {
        *(uint4*)&At[srow][sch]    = araw[k0 >> 5];
        *(uint4*)&Btile[srow][sch] = bn;
        if (k0 < 224) bn = *(const uint4*)(Bp + k0 + 32);
        __syncthreads();
        short8 a = *(short8*)&At[(w << 4) + c][quad << 3];
        #pragma unroll
        for (int nb = 0; nb < 4; ++nb) {
            short8 b = *(short8*)&Btile[(nb << 4) + c][quad << 3];
            acc[nb] = MFMA16(a, b, acc[nb]);
        }
        __syncthreads();
    }

    const int rl = (w << 4) + (quad << 2);
    // tau base for this thread's 4 consecutive key rows (rl..rl+3)
    const int tau = ((w >> 1) << 5) + (quad << 3) + ((w & 1) << 2);
    #pragma unroll
    for (int nb = 0; nb < 4; ++nb) {
        const int col = n0 + (nb << 4) + c;
        if (col < 256) {
            unsigned short* Cb = (mg < 1600) ? kbx + (size_t)mg * 256
                                             : kby + (size_t)(mg - 1600) * 256;
            #pragma unroll
            for (int r = 0; r < 4; ++r)
                Cb[(size_t)(rl + r) * 256 + col] = f2bf(acc[nb][r] * KSCALE);
        } else {
            unsigned lo = (unsigned)f2bf(acc[nb][0]) | ((unsigned)f2bf(acc[nb][1]) << 16);
            unsigned hi = (unsigned)f2bf(acc[nb][2]) | ((unsigned)f2bf(acc[nb][3]) << 16);
            unsigned short* Vb = (mg < 1600)
                ? vTx + (size_t)(col - 256) * 1600 + mg
                : vTy + (size_t)(col - 256) * 1024 + (mg - 1600);
            *(uint2*)(Vb + tau) = make_uint2(lo, hi);
        }
    }
}

// ---------------------------------------------------------------------------
// Batch-mean of support KV. Positional -> tau-permutation passes through.
// ---------------------------------------------------------------------------
__global__ __launch_bounds__(256) void kvmean_kernel(
    const unsigned short* __restrict__ kby, const unsigned short* __restrict__ vTy,
    unsigned short* __restrict__ km, unsigned short* __restrict__ vmT)
{
    int idx = blockIdx.x * 256 + threadIdx.x;
    if (idx < 65536) {
        float s = bf2f(kby[idx]) + bf2f(kby[idx + 65536]) +
                  bf2f(kby[idx + 131072]) + bf2f(kby[idx + 196608]);
        km[idx] = f2bf(0.25f * s);
    } else {
        int e = idx - 65536; int hd = e >> 8, r = e & 255;
        const unsigned short* p = vTy + ((size_t)hd << 10);
        float s = bf2f(p[r]) + bf2f(p[r + 256]) + bf2f(p[r + 512]) + bf2f(p[r + 768]);
        vmT[((size_t)hd << 8) + r] = f2bf(0.25f * s);
    }
}

// ---------------------------------------------------------------------------
// Barrier-free, LDS-free MFMA flash attention. Each wave owns 16 q-rows
// end-to-end: S^T = K@Q^T (4 MFMAs over all 64 keys), exp2 in-register,
// packed C-fragment IS the PV A-fragment (V stored tau-permuted), PV = 4
// MFMAs. K/V register ping-pong prefetch. Softmax denom via shfl_xor.
// Grid 1312 flat blocks (x: h*100+m; y: 800 + b*128 + h*16 + m).
// ---------------------------------------------------------------------------
__global__ __launch_bounds__(256) void attn_mfma(
    unsigned short* __restrict__ qxb, unsigned short* __restrict__ qyb,
    const unsigned short* __restrict__ kbx, const unsigned short* __restrict__ vTx,
    const unsigned short* __restrict__ km,  const unsigned short* __restrict__ vmT,
    const unsigned short* __restrict__ kby, const unsigned short* __restrict__ vTy)
{
    const int tid = threadIdx.x;
    const int lane = tid & 63, w = tid >> 6;
    const int c = lane & 15, quad = lane >> 4;

    const int bid = blockIdx.x;
    unsigned short* qb; const unsigned short *kb2, *vT2;
    int h, qoff, R2;
    if (bid < 800) {
        h = bid / 100; qoff = (bid - h * 100) * 64;
        qb = qxb; kb2 = km; vT2 = vmT; R2 = 256;
    } else {
        const int idx = bid - 800, b = idx >> 7, rem = idx & 127;
        h = rem >> 4; qoff = b * 1024 + (rem & 15) * 64;
        qb = qyb; kb2 = kby + (size_t)b * 65536; vT2 = vTy + b * 256;
        R2 = 1024;
    }

    // loop-invariant Q fragment (B-operand): row qoff+16w+c, d = quad*8..+8
    const int qrow = qoff + (w << 4) + c;
    const short8 qf = *(const short8*)(qb + (size_t)qrow * DIM + h * HD + (quad << 3));

    // K base: lane reads K rows (tile*64 + 16kb + c), d-offset quad*8
    const unsigned short* k1 = kbx + (size_t)c * DIM + h * HD + (quad << 3);
    const unsigned short* k2 = kb2 + (size_t)c * DIM + h * HD + (quad << 3);
    // V base (tau-permuted): row d = h*32 + 16nb + c, in-tile offset 32kc+8quad
    const unsigned short* v1b0 = vTx + (size_t)(h * HD + c) * 1600 + (quad << 3);
    const unsigned short* v1b1 = vTx + (size_t)(h * HD + 16 + c) * 1600 + (quad << 3);
    const unsigned short* v2b0 = vT2 + (size_t)(h * HD + c) * R2 + (quad << 3);
    const unsigned short* v2b1 = vT2 + (size_t)(h * HD + 16 + c) * R2 + (quad << 3);

    // va[0]=kc0/nb0, va[1]=kc0/nb1, va[2]=kc1/nb0, va[3]=kc1/nb1
    auto ld = [&](int t, short8* ka, short8* va) {
        const unsigned short* kp;
        const unsigned short *vb0, *vb1; int off;
        if (t < 25) { kp = k1 + ((size_t)t << 14); off = t << 6; vb0 = v1b0; vb1 = v1b1; }
        else { kp = k2 + ((size_t)(t - 25) << 14); off = (t - 25) << 6; vb0 = v2b0; vb1 = v2b1; }
        #pragma unroll
        for (int kb = 0; kb < 4; ++kb) ka[kb] = *(const short8*)(kp + (kb << 12));
        va[0] = *(const short8*)(vb0 + off);
        va[1] = *(const short8*)(vb1 + off);
        va[2] = *(const short8*)(vb0 + off + 32);
        va[3] = *(const short8*)(vb1 + off + 32);
    };

    float lsr = 0.f;
    f32x4 oacc[2] = {};
    const f32x4 zero = {0.f, 0.f, 0.f, 0.f};

    short8 kaA[4], vaA[4], kaB[4], vaB[4];
    ld(0, kaA, vaA);

    auto body = [&](int t, short8* ka, short8* va, short8* kan, short8* van) {
        f32x4 sacc[4];
        #pragma unroll
        for (int kb = 0; kb < 4; ++kb) sacc[kb] = MFMA16(ka[kb], qf, zero);
        if (t + 1 < 29) ld(t + 1, kan, van);   // prefetch next tile
        float p[16];
        #pragma unroll
        for (int kb = 0; kb < 4; ++kb) {
            p[4 * kb + 0] = EXP2(sacc[kb][0]);
            p[4 * kb + 1] = EXP2(sacc[kb][1]);
            p[4 * kb + 2] = EXP2(sacc[kb][2]);
            p[4 * kb + 3] = EXP2(sacc[kb][3]);
            lsr += (p[4 * kb + 0] + p[4 * kb + 1]) + (p[4 * kb + 2] + p[4 * kb + 3]);
        }
        U8 af0, af1;
        af0.u = make_uint4(pk2bf(p[0], p[1]), pk2bf(p[2], p[3]),
                           pk2bf(p[4], p[5]), pk2bf(p[6], p[7]));
        af1.u = make_uint4(pk2bf(p[8], p[9]), pk2bf(p[10], p[11]),
                           pk2bf(p[12], p[13]), pk2bf(p[14], p[15]));
        oacc[0] = MFMA16(af0.s, va[0], oacc[0]);
        oacc[1] = MFMA16(af0.s, va[1], oacc[1]);
        oacc[0] = MFMA16(af1.s, va[2], oacc[0]);
        oacc[1] = MFMA16(af1.s, va[3], oacc[1]);
    };

    for (int t = 0; t < 29; t += 2) {
        body(t, kaA, vaA, kaB, vaB);
        if (t + 1 < 29) body(t + 1, kaB, vaB, kaA, vaA);
    }

    // softmax denominators: lane holds partial for q_local = c; reduce quads
    lsr += __shfl_xor(lsr, 16);
    lsr += __shfl_xor(lsr, 32);

    // O fragment: lane holds q_local = 4*quad + r, d_local = 16*nb + c
    #pragma unroll
    for (int r = 0; r < 4; ++r) {
        const float inv = 1.0f / __shfl(lsr, (quad << 2) + r);
        const int row = qoff + (w << 4) + (quad << 2) + r;
        qb[(size_t)row * DIM + h * HD + c]      = f2bf(oacc[0][r] * inv);
        qb[(size_t)row * DIM + h * HD + 16 + c] = f2bf(oacc[1][r] * inv);
    }
}

// ---------------------------------------------------------------------------
// Output projection (x + y), fp32 out + bias. Flat 656 blocks.
// ---------------------------------------------------------------------------
__global__ __launch_bounds__(256) void proj_mfma(
    const unsigned short* __restrict__ qxb, const unsigned short* __restrict__ qyb,
    const unsigned short* __restrict__ projT, const float* __restrict__ bias,
    float* __restrict__ outx, float* __restrict__ outy)
{
    __shared__ __align__(16) unsigned short At[64][32];
    __shared__ __align__(16) unsigned short Btile[64][32];
    const int tid = threadIdx.x;
    const int lane = tid & 63, w = tid >> 6;
    const int c = lane & 15, quad = lane >> 4;
    const int srow = tid >> 2, sch = (tid & 3) << 3;

    const int bid = blockIdx.x;
    const int n0 = (bid & 3) << 6, mg = (bid >> 2) << 6;
    const unsigned short* Ab = (mg < 6400) ? qxb + (size_t)mg * 256
                                           : qyb + (size_t)(mg - 6400) * 256;
    float* Cf = (mg < 6400) ? outx + (size_t)mg * 256 : outy + (size_t)(mg - 6400) * 256;

    const unsigned short* Ap = Ab + (size_t)srow * 256 + sch;
    const unsigned short* Bp = projT + (size_t)(n0 + srow) * 256 + sch;

    uint4 an = *(const uint4*)Ap, bn = *(const uint4*)Bp;
    f32x4 acc[4] = {};
    for (int k0 = 0; k0 < 256; k0 += 32) {
        *(uint4*)&At[srow][sch]    = an;
        *(uint4*)&Btile[srow][sch] = bn;
        if (k0 < 224) { an = *(const uint4*)(Ap + k0 + 32); bn = *(const uint4*)(Bp + k0 + 32); }
        __syncthreads();
        short8 a = *(short8*)&At[(w << 4) + c][quad << 3];
        #pragma unroll
        for (int nb = 0; nb < 4; ++nb) {
            short8 b = *(short8*)&Btile[(nb << 4) + c][quad << 3];
            acc[nb] = MFMA16(a, b, acc[nb]);
        }
        __syncthreads();
    }
    const int rl = (w << 4) + (quad << 2);
    #pragma unroll
    for (int nb = 0; nb < 4; ++nb) {
        const int col = n0 + (nb << 4) + c;
        const float bv = bias[col];
        #pragma unroll
        for (int r = 0; r < 4; ++r)
            Cf[(size_t)(rl + r) * 256 + col] = acc[nb][r] + bv;
    }
}

// ---------------------------------------------------------------------------
extern "C" void kernel_launch(void* const* d_in, const int* in_sizes, int n_in,
                              void* d_out, int out_size, void* d_ws, size_t ws_size,
                              hipStream_t stream)
{
    const float* x      = (const float*)d_in[0];
    const float* y      = (const float*)d_in[1];
    const float* Wq     = (const float*)d_in[2];
    const float* Wkv    = (const float*)d_in[3];
    const float* sr_w   = (const float*)d_in[4];
    const float* sr_b   = (const float*)d_in[5];
    const float* ln_g   = (const float*)d_in[6];
    const float* ln_b   = (const float*)d_in[7];
    const float* proj_w = (const float*)d_in[8];
    const float* proj_b = (const float*)d_in[9];

    unsigned short* p = (unsigned short*)d_ws;
    unsigned short* WqT   = p;  p += 65536;
    unsigned short* WkvT  = p;  p += 131072;
    unsigned short* projT = p;  p += 65536;
    unsigned short* BwT   = p;  p += 262144;
    unsigned short* redx  = p;  p += 409600;     // 1600x256 (conv out, pre-LN)
    unsigned short* redy  = p;  p += 262144;     // 1024x256
    unsigned short* qxb   = p;  p += 1638400;    // Q_x -> attn out (in place)
    unsigned short* qyb   = p;  p += 1048576;
    unsigned short* kbx   = p;  p += 409600;     // K_x (pre-scaled), row-major
    unsigned short* vTx   = p;  p += 409600;     // V_x transposed+tau [(h*32+d)*1600+key]
    unsigned short* kby   = p;  p += 262144;
    unsigned short* vTy   = p;  p += 262144;     // pitch 1024, tau-permuted
    unsigned short* km    = p;  p += 65536;      // mean K_y (pre-scaled)
    unsigned short* vmT   = p;  p += 65536;      // mean V_y transposed+tau, pitch 256
    float* outx = (float*)d_out;
    float* outy = outx + 6400 * 256;

    prep_w<<<2048, 256, 0, stream>>>(Wq, Wkv, proj_w, sr_w, WqT, WkvT, projT, BwT);
    convq_kernel<<<820, 256, 0, stream>>>(x, y, BwT, sr_b, WqT, redx, redy, qxb, qyb);
    kvln_kernel<<<328, 256, 0, stream>>>(redx, redy, WkvT, ln_g, ln_b,
                                         kbx, vTx, kby, vTy);
    kvmean_kernel<<<512, 256, 0, stream>>>(kby, vTy, km, vmT);
    attn_mfma<<<1312, 256, 0, stream>>>(qxb, qyb, kbx, vTx, km, vmT, kby, vTy);
    proj_mfma<<<656, 256, 0, stream>>>(qxb, qyb, projT, proj_b, outx, outy);
}

// Round 7
// 168.722 us; speedup vs baseline: 1.6413x; 1.6413x over previous
//
#include <hip/hip_runtime.h>
#include <math.h>

#define DIM 256
#define HD 32
#define KSCALE (0.17677669529663687f * 1.44269504088896340736f)  /* SCALE*log2(e) */
#define EPS 1e-5f

typedef __attribute__((ext_vector_type(8))) short short8;   // 8 bf16 = 4 VGPRs
typedef __attribute__((ext_vector_type(4))) float f32x4;

union U8 { uint4 u; short8 s; };

__device__ inline unsigned short f2bf(float f) {
    union { float f; unsigned u; } v; v.f = f;
    unsigned r = v.u + 0x7FFF + ((v.u >> 16) & 1);   // RNE
    return (unsigned short)(r >> 16);
}
__device__ inline float bf2f(unsigned short h) {
    union { unsigned u; float f; } v; v.u = ((unsigned)h) << 16;
    return v.f;
}
// pack two fp32 -> two bf16 (round-half-up) in one dword: 3 VALU ops
__device__ inline unsigned pk2bf(float a, float b) {
    unsigned ua = __float_as_uint(a) + 0x8000u;
    unsigned ub = __float_as_uint(b) + 0x8000u;
    return __builtin_amdgcn_perm(ub, ua, 0x07060302u);  // {ub[31:16], ua[31:16]}
}
__device__ inline uint4 pk8bf(float4 a, float4 b) {
    return make_uint4(pk2bf(a.x, a.y), pk2bf(a.z, a.w),
                      pk2bf(b.x, b.y), pk2bf(b.z, b.w));
}
// unpack bf16x2 dword -> 2 fp32
__device__ inline void up2(unsigned u, float& a, float& b) {
    a = __uint_as_float(u << 16);
    b = __uint_as_float(u & 0xffff0000u);
}
// async global->LDS DMA, 16B/lane; lds dest must be wave-uniform (+lane*16 HW)
__device__ inline void gl_lds16(const unsigned short* g, unsigned short* l) {
    __builtin_amdgcn_global_load_lds(
        (const __attribute__((address_space(1))) unsigned int*)g,
        (__attribute__((address_space(3))) unsigned int*)l, 16, 0, 0);
}
#define MFMA16(a, b, c) __builtin_amdgcn_mfma_f32_16x16x32_bf16(a, b, c, 0, 0, 0)
#define EXP2(x) __builtin_amdgcn_exp2f(x)

// ---------------------------------------------------------------------------
// Weights prep: transposed bf16 WqT/WkvT/projT [N][K], conv BwT[o][q*256+i].
// Grid 2048 x 256 (exact 524288 elements).
// ---------------------------------------------------------------------------
__global__ __launch_bounds__(256) void prep_w(
    const float* __restrict__ Wq, const float* __restrict__ Wkv,
    const float* __restrict__ projw, const float* __restrict__ srw,
    unsigned short* __restrict__ WqT, unsigned short* __restrict__ WkvT,
    unsigned short* __restrict__ projT, unsigned short* __restrict__ BwT)
{
    int idx = blockIdx.x * 256 + threadIdx.x;
    if (idx < 65536) { int n = idx >> 8, k = idx & 255; WqT[idx] = f2bf(Wq[(k << 8) + n]); return; }
    idx -= 65536;
    if (idx < 131072) { int n = idx >> 8, k = idx & 255; WkvT[idx] = f2bf(Wkv[(k << 9) + n]); return; }
    idx -= 131072;
    if (idx < 65536) { int n = idx >> 8, k = idx & 255; projT[idx] = f2bf(projw[(k << 8) + n]); return; }
    idx -= 65536;
    { int o = idx >> 10, rem = idx & 1023, q = rem >> 8, i = rem & 255;
      BwT[idx] = f2bf(srw[(o << 10) + (i << 2) + q]); }
}

// ---------------------------------------------------------------------------
// Merged conv (im2col, K=1024) + q-projection (K=256), A staged from fp32
// with on-the-fly bf16 pack. Grid 820 flat blocks.
// ---------------------------------------------------------------------------
__global__ __launch_bounds__(256) void convq_kernel(
    const float* __restrict__ x, const float* __restrict__ y,
    const unsigned short* __restrict__ BwT, const float* __restrict__ srb,
    const unsigned short* __restrict__ WqT,
    unsigned short* __restrict__ redx, unsigned short* __restrict__ redy,
    unsigned short* __restrict__ qxb, unsigned short* __restrict__ qyb)
{
    __shared__ __align__(16) unsigned short At[64][32];
    __shared__ __align__(16) unsigned short Btile[64][32];
    const int tid = threadIdx.x;
    const int lane = tid & 63, w = tid >> 6;
    const int c = lane & 15, quad = lane >> 4;
    const int srow = tid >> 2, sch = (tid & 3) << 3;
    const int bid = blockIdx.x;
    f32x4 acc[4] = {};
    const int rl = (w << 4) + (quad << 2);

    if (bid < 164) {
        // ---------------- conv path ----------------
        const int n0 = (bid & 3) << 6, myi = bid >> 2;
        const float* Xb; unsigned short* Cb; int W, W2, m0;
        if (myi < 25) { Xb = x; Cb = redx; W = 80; W2 = 40; m0 = myi * 64; }
        else {
            const int r = myi - 25, b = r >> 2;
            Xb = y + (size_t)b * 262144; Cb = redy + (size_t)b * 65536;
            W = 32; W2 = 16; m0 = (r & 3) * 64;
        }
        const int p = m0 + srow;
        const int oy = p / W2, ox = p - oy * W2;
        const unsigned short* Bp = BwT + (size_t)(n0 + srow) * 1024 + sch;

        auto addrA = [&](int k0) {
            const int qq = k0 >> 8;
            const int rrow = (2 * oy + (qq >> 1)) * W + 2 * ox + (qq & 1);
            return Xb + (size_t)rrow * DIM + (k0 & 255) + sch;
        };

        const float* ap = addrA(0);
        float4 a0 = *(const float4*)ap, a1 = *(const float4*)(ap + 4);
        uint4 bn = *(const uint4*)Bp;
        for (int k0 = 0; k0 < 1024; k0 += 32) {
            *(uint4*)&At[srow][sch]    = pk8bf(a0, a1);
            *(uint4*)&Btile[srow][sch] = bn;
            if (k0 < 992) {
                const float* np = addrA(k0 + 32);
                a0 = *(const float4*)np; a1 = *(const float4*)(np + 4);
                bn = *(const uint4*)(Bp + k0 + 32);
            }
            __syncthreads();
            short8 a = *(short8*)&At[(w << 4) + c][quad << 3];
            #pragma unroll
            for (int nb = 0; nb < 4; ++nb) {
                short8 b = *(short8*)&Btile[(nb << 4) + c][quad << 3];
                acc[nb] = MFMA16(a, b, acc[nb]);
            }
            __syncthreads();
        }
        #pragma unroll
        for (int nb = 0; nb < 4; ++nb) {
            const int col = n0 + (nb << 4) + c;
            const float bv = srb[col];
            #pragma unroll
            for (int r = 0; r < 4; ++r)
                Cb[(size_t)(m0 + rl + r) * DIM + col] = f2bf(acc[nb][r] + bv);
        }
    } else {
        // ---------------- q-projection path ----------------
        const int r = bid - 164;
        const int n0 = (r & 3) << 6, mg = (r >> 2) << 6;
        const float* Ab = (mg < 6400) ? x + (size_t)mg * 256
                                      : y + (size_t)(mg - 6400) * 256;
        unsigned short* Cb = (mg < 6400) ? qxb + (size_t)mg * 256
                                         : qyb + (size_t)(mg - 6400) * 256;
        const float* Ap = Ab + (size_t)srow * 256 + sch;
        const unsigned short* Bp = WqT + (size_t)(n0 + srow) * 256 + sch;

        float4 a0 = *(const float4*)Ap, a1 = *(const float4*)(Ap + 4);
        uint4 bn = *(const uint4*)Bp;
        for (int k0 = 0; k0 < 256; k0 += 32) {
            *(uint4*)&At[srow][sch]    = pk8bf(a0, a1);
            *(uint4*)&Btile[srow][sch] = bn;
            if (k0 < 224) {
                a0 = *(const float4*)(Ap + k0 + 32);
                a1 = *(const float4*)(Ap + k0 + 36);
                bn = *(const uint4*)(Bp + k0 + 32);
            }
            __syncthreads();
            short8 a = *(short8*)&At[(w << 4) + c][quad << 3];
            #pragma unroll
            for (int nb = 0; nb < 4; ++nb) {
                short8 b = *(short8*)&Btile[(nb << 4) + c][quad << 3];
                acc[nb] = MFMA16(a, b, acc[nb]);
            }
            __syncthreads();
        }
        #pragma unroll
        for (int nb = 0; nb < 4; ++nb) {
            const int col = n0 + (nb << 4) + c;
            #pragma unroll
            for (int r = 0; r < 4; ++r)
                Cb[(size_t)(rl + r) * 256 + col] = f2bf(acc[nb][r]);
        }
    }
}

// ---------------------------------------------------------------------------
// KV projection with fused LayerNorm on A-rows. Outputs are written in the
// attention's swizzled per-(head, 64-key-tile) 4KB-block layouts:
//   K: ksw[h][tile][(d>>3)*64 + key]*8 + (d&7)          (K pre-scaled by KSCALE)
//   V: vsw[h][tile][((kc*4+q)*32 + d)*8 + u], (kc,q,u) = tau(key) split
// so attn stages them with two coalesced global_load_lds per wave per tile.
// ---------------------------------------------------------------------------
__global__ __launch_bounds__(256) void kvln_kernel(
    const unsigned short* __restrict__ redx, const unsigned short* __restrict__ redy,
    const unsigned short* __restrict__ WkvT,
    const float* __restrict__ g, const float* __restrict__ bta,
    unsigned short* __restrict__ kswx, unsigned short* __restrict__ vswx,
    unsigned short* __restrict__ kswy, unsigned short* __restrict__ vswy)
{
    __shared__ __align__(16) unsigned short At[64][32];
    __shared__ __align__(16) unsigned short Btile[64][32];
    const int tid = threadIdx.x;
    const int lane = tid & 63, w = tid >> 6;
    const int c = lane & 15, quad = lane >> 4;
    const int srow = tid >> 2, sch = (tid & 3) << 3;
    const int bid = blockIdx.x;
    const int n0 = (bid & 7) << 6, mg = (bid >> 3) << 6;
    const unsigned short* Ab = (mg < 1600) ? redx + (size_t)mg * 256
                                           : redy + (size_t)(mg - 1600) * 256;
    const unsigned short* Arow = Ab + (size_t)srow * 256 + sch;

    // ---- row stats ----
    uint4 araw[8];
    float s1 = 0.f, s2 = 0.f;
    #pragma unroll
    for (int ci = 0; ci < 8; ++ci) {
        araw[ci] = *(const uint4*)(Arow + (ci << 5));
        const unsigned* du = (const unsigned*)&araw[ci];
        #pragma unroll
        for (int dd = 0; dd < 4; ++dd) {
            float a, b; up2(du[dd], a, b);
            s1 += a + b; s2 += a * a + b * b;
        }
    }
    s1 += __shfl_xor(s1, 1); s1 += __shfl_xor(s1, 2);
    s2 += __shfl_xor(s2, 1); s2 += __shfl_xor(s2, 2);
    const float mean = s1 * (1.0f / 256.0f);
    const float var  = s2 * (1.0f / 256.0f) - mean * mean;
    const float rstd = rsqrtf(var + EPS);

    // ---- apply LN, repack to bf16 ----
    #pragma unroll
    for (int ci = 0; ci < 8; ++ci) {
        const int ch = (ci << 5) + sch;
        float4 g0 = *(const float4*)(g + ch),   g1 = *(const float4*)(g + ch + 4);
        float4 b0 = *(const float4*)(bta + ch), b1 = *(const float4*)(bta + ch + 4);
        const unsigned* du = (const unsigned*)&araw[ci];
        float v[8];
        #pragma unroll
        for (int dd = 0; dd < 4; ++dd) up2(du[dd], v[2 * dd], v[2 * dd + 1]);
        float4 o0 = make_float4(fmaf((v[0] - mean) * rstd, g0.x, b0.x),
                                fmaf((v[1] - mean) * rstd, g0.y, b0.y),
                                fmaf((v[2] - mean) * rstd, g0.z, b0.z),
                                fmaf((v[3] - mean) * rstd, g0.w, b0.w));
        float4 o1 = make_float4(fmaf((v[4] - mean) * rstd, g1.x, b1.x),
                                fmaf((v[5] - mean) * rstd, g1.y, b1.y),
                                fmaf((v[6] - mean) * rstd, g1.z, b1.z),
                                fmaf((v[7] - mean) * rstd, g1.w, b1.w));
        araw[ci] = pk8bf(o0, o1);
    }

    // ---- GEMM k-loop ----
    const unsigned short* Bp = WkvT + (size_t)(n0 + srow) * 256 + sch;
    uint4 bn = *(const uint4*)Bp;
    f32x4 acc[4] = {};
    for (int k0 = 0; k0 < 256; k0 += 32) {
        *(uint4*)&At[srow][sch]    = araw[k0 >> 5];
        *(uint4*)&Btile[srow][sch] = bn;
        if (k0 < 224) bn = *(const uint4*)(Bp + k0 + 32);
        __syncthreads();
        short8 a = *(short8*)&At[(w << 4) + c][quad << 3];
        #pragma unroll
        for (int nb = 0; nb < 4; ++nb) {
            short8 b = *(short8*)&Btile[(nb << 4) + c][quad << 3];
            acc[nb] = MFMA16(a, b, acc[nb]);
        }
        __syncthreads();
    }

    const int rl = (w << 4) + (quad << 2);        // first of 4 key rows (in-tile)
    const int r0 = mg - 1600;                     // y row offset (if y)
    #pragma unroll
    for (int nb = 0; nb < 4; ++nb) {
        const int col = n0 + (nb << 4) + c;
        if (col < 256) {
            const int hh = col >> 5, d = col & 31;
            unsigned short* base = (mg < 1600)
                ? kswx + ((size_t)(hh * 25 + (mg >> 6)) << 11)
                : kswy + ((size_t)(r0 >> 8) << 16) + ((size_t)((hh << 2) + ((r0 >> 6) & 3)) << 11);
            unsigned short* dst = base + (((d >> 3) << 9)) + (d & 7);
            #pragma unroll
            for (int r = 0; r < 4; ++r)
                dst[(rl + r) << 3] = f2bf(acc[nb][r] * KSCALE);
        } else {
            const int hd = col - 256, hv = hd >> 5, d = hd & 31;
            unsigned short* base = (mg < 1600)
                ? vswx + ((size_t)(hv * 25 + (mg >> 6)) << 11)
                : vswy + ((size_t)(r0 >> 8) << 16) + ((size_t)((hv << 2) + ((r0 >> 6) & 3)) << 11);
            // tau(rl): kc,qq,u split
            const int j0 = ((w >> 1) << 5) + (quad << 3) + ((w & 1) << 2);
            const int kc = j0 >> 5, qq = (j0 >> 3) & 3, u = j0 & 7;
            unsigned lo = (unsigned)f2bf(acc[nb][0]) | ((unsigned)f2bf(acc[nb][1]) << 16);
            unsigned hi = (unsigned)f2bf(acc[nb][2]) | ((unsigned)f2bf(acc[nb][3]) << 16);
            *(uint2*)(base + ((size_t)(((kc << 2) + qq) * 32 + d) << 3) + u) =
                make_uint2(lo, hi);
        }
    }
}

// ---------------------------------------------------------------------------
// Batch-mean of support KV in swizzled layout (both halves contiguous,
// batch stride 65536). Grid 512 x 256.
// ---------------------------------------------------------------------------
__global__ __launch_bounds__(256) void kvmean_kernel(
    const unsigned short* __restrict__ kswy, const unsigned short* __restrict__ vswy,
    unsigned short* __restrict__ kmsw, unsigned short* __restrict__ vmsw)
{
    int idx = blockIdx.x * 256 + threadIdx.x;
    const unsigned short* s; unsigned short* dv; int e;
    if (idx < 65536) { s = kswy; dv = kmsw; e = idx; }
    else             { s = vswy; dv = vmsw; e = idx - 65536; }
    float sm = bf2f(s[e]) + bf2f(s[e + 65536]) + bf2f(s[e + 131072]) + bf2f(s[e + 196608]);
    dv[e] = f2bf(0.25f * sm);
}

// ---------------------------------------------------------------------------
// MFMA flash attention: K/V tiles staged block-shared into double-buffered
// LDS via coalesced global_load_lds (2 insts/wave/tile), ONE barrier per
// tile; P stays in-register (tau trick, verified r6); exp2 softmax with
// pre-scaled K. Grid 1312 flat blocks (x: h*100+m; y: 800 + b*128+h*16+m).
// ---------------------------------------------------------------------------
__global__ __launch_bounds__(256) void attn_mfma(
    unsigned short* __restrict__ qxb, unsigned short* __restrict__ qyb,
    const unsigned short* __restrict__ kswx, const unsigned short* __restrict__ vswx,
    const unsigned short* __restrict__ kmsw, const unsigned short* __restrict__ vmsw,
    const unsigned short* __restrict__ kswy, const unsigned short* __restrict__ vswy)
{
    __shared__ __align__(16) unsigned short Kt[2][2048];  // [quad][key][8d]
    __shared__ __align__(16) unsigned short Vt[2][2048];  // [kc][q][d][8keys]

    const int tid = threadIdx.x;
    const int lane = tid & 63, w = tid >> 6;
    const int c = lane & 15, quad = lane >> 4;

    const int bid = blockIdx.x;
    unsigned short* qb; const unsigned short *k1, *v1, *k2, *v2;
    int h, qoff;
    if (bid < 800) {
        h = bid / 100; qoff = (bid - h * 100) * 64;
        qb = qxb;
        k1 = kswx + ((size_t)h * 25 << 11); v1 = vswx + ((size_t)h * 25 << 11);
        k2 = kmsw + ((size_t)h << 13);      v2 = vmsw + ((size_t)h << 13);
    } else {
        const int idx = bid - 800, b = idx >> 7, rem = idx & 127;
        h = rem >> 4; qoff = b * 1024 + (rem & 15) * 64;
        qb = qyb;
        k1 = kswx + ((size_t)h * 25 << 11); v1 = vswx + ((size_t)h * 25 << 11);
        k2 = kswy + ((size_t)b << 16) + ((size_t)h << 13);
        v2 = vswy + ((size_t)b << 16) + ((size_t)h << 13);
    }

    // loop-invariant Q fragment (B-operand): row qoff+16w+c, d = quad*8..+8
    const int qrow = qoff + (w << 4) + c;
    const short8 qf = *(const short8*)(qb + (size_t)qrow * DIM + h * HD + (quad << 3));

    const int lel = (w << 9) + (lane << 3);   // staged element offset (w*512 + lane*8)

    auto stage = [&](int t, int pb) {
        const unsigned short *ks, *vs;
        if (t < 25) { ks = k1 + (t << 11); vs = v1 + (t << 11); }
        else        { ks = k2 + ((t - 25) << 11); vs = v2 + ((t - 25) << 11); }
        gl_lds16(ks + lel, &Kt[pb][w << 9]);
        gl_lds16(vs + lel, &Vt[pb][w << 9]);
    };

    float lsr = 0.f;
    f32x4 oacc[2] = {};
    const f32x4 zero = {0.f, 0.f, 0.f, 0.f};

    stage(0, 0);
    __syncthreads();

    for (int t = 0; t < 29; ++t) {
        const int pb = t & 1;
        if (t < 28) stage(t + 1, pb ^ 1);

        // ---- S^T: 4 MFMAs over all 64 keys for this wave's 16 q-rows ----
        const unsigned short* Kp = &Kt[pb][quad << 9];
        f32x4 sacc[4];
        #pragma unroll
        for (int kb = 0; kb < 4; ++kb) {
            short8 ka = *(const short8*)(Kp + (((kb << 4) + c) << 3));
            sacc[kb] = MFMA16(ka, qf, zero);
        }
        // ---- exp2 + in-register pack (tau order) ----
        float p[16];
        #pragma unroll
        for (int kb = 0; kb < 4; ++kb) {
            p[4 * kb + 0] = EXP2(sacc[kb][0]);
            p[4 * kb + 1] = EXP2(sacc[kb][1]);
            p[4 * kb + 2] = EXP2(sacc[kb][2]);
            p[4 * kb + 3] = EXP2(sacc[kb][3]);
            lsr += (p[4 * kb + 0] + p[4 * kb + 1]) + (p[4 * kb + 2] + p[4 * kb + 3]);
        }
        U8 af0, af1;
        af0.u = make_uint4(pk2bf(p[0], p[1]), pk2bf(p[2], p[3]),
                           pk2bf(p[4], p[5]), pk2bf(p[6], p[7]));
        af1.u = make_uint4(pk2bf(p[8], p[9]), pk2bf(p[10], p[11]),
                           pk2bf(p[12], p[13]), pk2bf(p[14], p[15]));
        // ---- PV: 4 MFMAs, V fragments from LDS ----
        const unsigned short* Vp = &Vt[pb][0];
        short8 v00 = *(const short8*)(Vp + (((quad << 5) + c) << 3));
        short8 v01 = *(const short8*)(Vp + (((quad << 5) + 16 + c) << 3));
        short8 v10 = *(const short8*)(Vp + ((((4 + quad) << 5) + c) << 3));
        short8 v11 = *(const short8*)(Vp + ((((4 + quad) << 5) + 16 + c) << 3));
        oacc[0] = MFMA16(af0.s, v00, oacc[0]);
        oacc[1] = MFMA16(af0.s, v01, oacc[1]);
        oacc[0] = MFMA16(af1.s, v10, oacc[0]);
        oacc[1] = MFMA16(af1.s, v11, oacc[1]);

        __syncthreads();   // drains t+1 staging (hidden by compute); frees buf pb
    }

    // softmax denominators: lane holds partial for q_local = c; reduce quads
    lsr += __shfl_xor(lsr, 16);
    lsr += __shfl_xor(lsr, 32);

    // O fragment: lane holds q_local = 4*quad + r, d_local = 16*nb + c
    #pragma unroll
    for (int r = 0; r < 4; ++r) {
        const float inv = 1.0f / __shfl(lsr, (quad << 2) + r);
        const int row = qoff + (w << 4) + (quad << 2) + r;
        qb[(size_t)row * DIM + h * HD + c]      = f2bf(oacc[0][r] * inv);
        qb[(size_t)row * DIM + h * HD + 16 + c] = f2bf(oacc[1][r] * inv);
    }
}

// ---------------------------------------------------------------------------
// Output projection (x + y), fp32 out + bias. Flat 656 blocks.
// ---------------------------------------------------------------------------
__global__ __launch_bounds__(256) void proj_mfma(
    const unsigned short* __restrict__ qxb, const unsigned short* __restrict__ qyb,
    const unsigned short* __restrict__ projT, const float* __restrict__ bias,
    float* __restrict__ outx, float* __restrict__ outy)
{
    __shared__ __align__(16) unsigned short At[64][32];
    __shared__ __align__(16) unsigned short Btile[64][32];
    const int tid = threadIdx.x;
    const int lane = tid & 63, w = tid >> 6;
    const int c = lane & 15, quad = lane >> 4;
    const int srow = tid >> 2, sch = (tid & 3) << 3;

    const int bid = blockIdx.x;
    const int n0 = (bid & 3) << 6, mg = (bid >> 2) << 6;
    const unsigned short* Ab = (mg < 6400) ? qxb + (size_t)mg * 256
                                           : qyb + (size_t)(mg - 6400) * 256;
    float* Cf = (mg < 6400) ? outx + (size_t)mg * 256 : outy + (size_t)(mg - 6400) * 256;

    const unsigned short* Ap = Ab + (size_t)srow * 256 + sch;
    const unsigned short* Bp = projT + (size_t)(n0 + srow) * 256 + sch;

    uint4 an = *(const uint4*)Ap, bn = *(const uint4*)Bp;
    f32x4 acc[4] = {};
    for (int k0 = 0; k0 < 256; k0 += 32) {
        *(uint4*)&At[srow][sch]    = an;
        *(uint4*)&Btile[srow][sch] = bn;
        if (k0 < 224) { an = *(const uint4*)(Ap + k0 + 32); bn = *(const uint4*)(Bp + k0 + 32); }
        __syncthreads();
        short8 a = *(short8*)&At[(w << 4) + c][quad << 3];
        #pragma unroll
        for (int nb = 0; nb < 4; ++nb) {
            short8 b = *(short8*)&Btile[(nb << 4) + c][quad << 3];
            acc[nb] = MFMA16(a, b, acc[nb]);
        }
        __syncthreads();
    }
    const int rl = (w << 4) + (quad << 2);
    #pragma unroll
    for (int nb = 0; nb < 4; ++nb) {
        const int col = n0 + (nb << 4) + c;
        const float bv = bias[col];
        #pragma unroll
        for (int r = 0; r < 4; ++r)
            Cf[(size_t)(rl + r) * 256 + col] = acc[nb][r] + bv;
    }
}

// ---------------------------------------------------------------------------
extern "C" void kernel_launch(void* const* d_in, const int* in_sizes, int n_in,
                              void* d_out, int out_size, void* d_ws, size_t ws_size,
                              hipStream_t stream)
{
    const float* x      = (const float*)d_in[0];
    const float* y      = (const float*)d_in[1];
    const float* Wq     = (const float*)d_in[2];
    const float* Wkv    = (const float*)d_in[3];
    const float* sr_w   = (const float*)d_in[4];
    const float* sr_b   = (const float*)d_in[5];
    const float* ln_g   = (const float*)d_in[6];
    const float* ln_b   = (const float*)d_in[7];
    const float* proj_w = (const float*)d_in[8];
    const float* proj_b = (const float*)d_in[9];

    unsigned short* p = (unsigned short*)d_ws;
    unsigned short* WqT   = p;  p += 65536;
    unsigned short* WkvT  = p;  p += 131072;
    unsigned short* projT = p;  p += 65536;
    unsigned short* BwT   = p;  p += 262144;
    unsigned short* redx  = p;  p += 409600;     // 1600x256 (conv out, pre-LN)
    unsigned short* redy  = p;  p += 262144;     // 1024x256
    unsigned short* qxb   = p;  p += 1638400;    // Q_x -> attn out (in place)
    unsigned short* qyb   = p;  p += 1048576;
    unsigned short* kswx  = p;  p += 409600;     // K_x swizzled [h][25 tiles][2048]
    unsigned short* vswx  = p;  p += 409600;     // V_x swizzled [h][25 tiles][2048]
    unsigned short* kswy  = p;  p += 262144;     // [b][h][4][2048]
    unsigned short* vswy  = p;  p += 262144;
    unsigned short* kmsw  = p;  p += 65536;      // mean K_y swizzled [h][4][2048]
    unsigned short* vmsw  = p;  p += 65536;
    float* outx = (float*)d_out;
    float* outy = outx + 6400 * 256;

    prep_w<<<2048, 256, 0, stream>>>(Wq, Wkv, proj_w, sr_w, WqT, WkvT, projT, BwT);
    convq_kernel<<<820, 256, 0, stream>>>(x, y, BwT, sr_b, WqT, redx, redy, qxb, qyb);
    kvln_kernel<<<328, 256, 0, stream>>>(redx, redy, WkvT, ln_g, ln_b,
                                         kswx, vswx, kswy, vswy);
    kvmean_kernel<<<512, 256, 0, stream>>>(kswy, vswy, kmsw, vmsw);
    attn_mfma<<<1312, 256, 0, stream>>>(qxb, qyb, kswx, vswx, kmsw, vmsw, kswy, vswy);
    proj_mfma<<<656, 256, 0, stream>>>(qxb, qyb, projT, proj_b, outx, outy);
}